// Round 4
// baseline (303.114 us; speedup 1.0000x reference)
//
#include <hip/hip_runtime.h>
#include <stdint.h>

// Problem constants
#define NMOL 4096
#define NF 124
#define NT 8
#define ROWV 125               // x_padded row stride in floats

// ws layout (bytes)
#define WS_DCONST 0            // float[8]
#define WS_W1S    64           // ushort[8*64*128] bf16, XOR-16 swizzled   (128 KB)
#define WS_W2T    131136       // ushort[8*16*64]  bf16, [t][g][h]         (16 KB)

#define HS 72                  // h1 row stride (bf16 shorts)

typedef __attribute__((ext_vector_type(8))) short short8;
typedef __attribute__((ext_vector_type(4))) float floatx4;
typedef __attribute__((ext_vector_type(4))) unsigned int uint4v;

__device__ __forceinline__ unsigned short f2bf(float f) {
    unsigned u = __builtin_bit_cast(unsigned, f);
    u += 0x7fffu + ((u >> 16) & 1u);
    return (unsigned short)(u >> 16);
}

// ---------------- K1: setup (fp32 constants + weight prep) ----------------
// b==0: dconst; b in 1..8: type t=b-1 -> W1S (bf16 swizzled) + W2T (bf16 [g][h])
__global__ __launch_bounds__(256) void k_setup(const float* __restrict__ W1,
                                               const float* __restrict__ b1,
                                               const float* __restrict__ W2,
                                               const float* __restrict__ b2,
                                               const float* __restrict__ W3,
                                               const float* __restrict__ b3,
                                               float* __restrict__ dconst,
                                               unsigned short* __restrict__ W1S,
                                               unsigned short* __restrict__ W2T) {
    int tid = threadIdx.x, b = blockIdx.x;
    if (b == 0) {
        __shared__ float c[NT];
        if (tid < 128) {           // exact fp32 constant c_t = MLP_t(0)
            int t = tid >> 4, g = tid & 15;
            float acc = b2[t * 16 + g];
            for (int h = 0; h < 64; ++h) {
                float h1 = b1[t * 64 + h];
                h1 = h1 > 0.f ? h1 : 0.f;
                acc += h1 * W2[(size_t)t * 1024 + h * 16 + g];
            }
            float h2 = acc > 0.f ? acc : 0.f;
            float v = h2 * W3[t * 16 + g];
            #pragma unroll
            for (int off = 1; off < 16; off <<= 1) v += __shfl_xor(v, off);
            if (g == 0) c[t] = v + b3[t];
        }
        __syncthreads();
        if (tid == 0) {
            float T_ = 0.f;
            for (int i = 0; i < NT; ++i) T_ += c[i];
            for (int i = 0; i < NT; ++i) dconst[i] = T_ - c[i];
        }
    } else {
        int t = b - 1;
        // W1 -> W1S: [h][chunk p = c ^ (h&15)][8 shorts], f padded to 128 w/ zeros
        const float* w1g = W1 + (size_t)t * NF * 64;
        unsigned short* dst = W1S + (size_t)t * 8192;
        for (int id = tid; id < 1024; id += 256) {   // (h, chunk c)
            int h = id >> 4, cc = id & 15;
            unsigned u[4];
            #pragma unroll
            for (int j = 0; j < 4; ++j) {
                int f0 = cc * 8 + 2 * j;
                unsigned short lo = (f0 < NF)     ? f2bf(w1g[f0 * 64 + h])       : (unsigned short)0;
                unsigned short hi = (f0 + 1 < NF) ? f2bf(w1g[(f0 + 1) * 64 + h]) : (unsigned short)0;
                u[j] = (unsigned)lo | ((unsigned)hi << 16);
            }
            int p = cc ^ (h & 15);
            *(uint4v*)(dst + h * 128 + p * 8) = (uint4v){u[0], u[1], u[2], u[3]};
        }
        // W2 -> W2T: [t][g][h]
        unsigned short* d2 = W2T + (size_t)t * 1024;
        for (int i = tid; i < 1024; i += 256) {
            int g = i >> 6, h = i & 63;
            d2[i] = f2bf(W2[(size_t)t * 1024 + h * 16 + g]);
        }
    }
}

// ---------------- K2: single-pass streaming MLP (all 8 types per tile) ----------------
// Block = 128 consecutive atoms = 2 whole molecules. Each wave owns rows
// [32w, 32w+32) of sA/sH end-to-end -> no barriers until the final reduce.
__global__ __launch_bounds__(256, 3) void k_main(const float* __restrict__ x,
                                                 const float* __restrict__ mask,
                                                 const unsigned short* __restrict__ W1S,
                                                 const float* __restrict__ b1,
                                                 const unsigned short* __restrict__ W2T,
                                                 const float* __restrict__ b2,
                                                 const float* __restrict__ W3,
                                                 const float* __restrict__ b3,
                                                 const float* __restrict__ dconst,
                                                 float* __restrict__ out) {
    __shared__ unsigned short sA[128 * 128];   // bf16 feats, XOR-16 swizzled (32 KB)
    __shared__ unsigned short sH[128 * HS];    // bf16 h1 (18 KB)
    __shared__ unsigned char  sMeta[128];      // kept ? type : 255
    __shared__ float          sPart[4];

    int b    = blockIdx.x;
    int tid  = threadIdx.x;
    int wv   = tid >> 6;
    int lane = tid & 63;
    int quad = lane >> 4, l15 = lane & 15;
    int rowbase = wv * 32;

    // ---- meta: type + mask for this wave's 32 rows ----
    if (lane < 32) {
        int row  = rowbase + lane;
        int atom = b * 128 + row;
        float tf = x[(size_t)atom * ROWV];
        float m  = mask[atom];
        sMeta[row] = (m != 0.f) ? (unsigned char)(int)tf : (unsigned char)255;
    }

    // ---- stage this wave's 32 rows -> bf16 swizzled LDS (coalesced dword loads) ----
    {
        const float* xb = x + (size_t)b * 128 * ROWV;
        #pragma unroll 8
        for (int r = 0; r < 32; ++r) {
            int row = rowbase + r;
            unsigned pk = 0u;
            if (lane < 62) {
                const float* src = xb + (size_t)row * ROWV + 1 + 2 * lane;
                pk = (unsigned)f2bf(src[0]) | ((unsigned)f2bf(src[1]) << 16);
            }
            int c = lane >> 2;   // 16-B chunk index 0..15
            *(unsigned*)(sA + row * 128 + ((c ^ (row & 15)) << 3) + 2 * (lane & 3)) = pk;
        }
    }

    float wAcc = 0.f;

    #pragma unroll 1
    for (int t = 0; t < NT; ++t) {
        const unsigned short* w1t = W1S + (size_t)t * 8192;
        const unsigned short* w2t = W2T + (size_t)t * 1024;

        float b1v[4];
        #pragma unroll
        for (int n = 0; n < 4; ++n) b1v[n] = b1[t * 64 + n * 16 + l15];

        // ---- layer 1: [32x128] x [128x64], B-frags direct from L2-hot W1S ----
        floatx4 c1[2][4];
        #pragma unroll
        for (int m = 0; m < 2; ++m)
            #pragma unroll
            for (int n = 0; n < 4; ++n) c1[m][n] = (floatx4)0.f;

        #pragma unroll
        for (int ks = 0; ks < 4; ++ks) {
            int pc = ((ks * 4 + quad) ^ l15) << 3;
            short8 a0 = *(const short8*)(sA + (rowbase + l15) * 128 + pc);
            short8 a1 = *(const short8*)(sA + (rowbase + 16 + l15) * 128 + pc);
            short8 bf[4];
            #pragma unroll
            for (int n = 0; n < 4; ++n)
                bf[n] = *(const short8*)(w1t + (n * 16 + l15) * 128 + pc);
            #pragma unroll
            for (int n = 0; n < 4; ++n) {
                c1[0][n] = __builtin_amdgcn_mfma_f32_16x16x32_bf16(a0, bf[n], c1[0][n], 0, 0, 0);
                c1[1][n] = __builtin_amdgcn_mfma_f32_16x16x32_bf16(a1, bf[n], c1[1][n], 0, 0, 0);
            }
        }

        // ---- h1 = relu(c1 + b1) -> sH (own-wave rows; in-order DS, no barrier) ----
        #pragma unroll
        for (int m = 0; m < 2; ++m)
            #pragma unroll
            for (int n = 0; n < 4; ++n) {
                int col = n * 16 + l15;
                #pragma unroll
                for (int r = 0; r < 4; ++r) {
                    float v = c1[m][n][r] + b1v[n];
                    v = v > 0.f ? v : 0.f;
                    sH[(rowbase + m * 16 + quad * 4 + r) * HS + col] = f2bf(v);
                }
            }

        // ---- layer 2: [32x64] x [64x16], B-frag direct from W2T ----
        floatx4 c2[2];
        c2[0] = (floatx4)0.f; c2[1] = (floatx4)0.f;
        #pragma unroll
        for (int ks = 0; ks < 2; ++ks) {
            int ko = ks * 32 + quad * 8;
            short8 a0 = *(const short8*)(sH + (rowbase + l15) * HS + ko);
            short8 a1 = *(const short8*)(sH + (rowbase + 16 + l15) * HS + ko);
            short8 bw = *(const short8*)(w2t + l15 * 64 + ko);
            c2[0] = __builtin_amdgcn_mfma_f32_16x16x32_bf16(a0, bw, c2[0], 0, 0, 0);
            c2[1] = __builtin_amdgcn_mfma_f32_16x16x32_bf16(a1, bw, c2[1], 0, 0, 0);
        }

        // ---- layer 3 + per-row type select ----
        float b2v = b2[t * 16 + l15];
        float w3v = W3[t * 16 + l15];
        float dct = dconst[t] + b3[t];
        #pragma unroll
        for (int m = 0; m < 2; ++m) {
            float h2v[4];
            #pragma unroll
            for (int r = 0; r < 4; ++r) {
                float v = c2[m][r] + b2v;
                v = v > 0.f ? v : 0.f;
                h2v[r] = v * w3v;
            }
            #pragma unroll
            for (int off = 1; off < 16; off <<= 1)
                #pragma unroll
                for (int r = 0; r < 4; ++r) h2v[r] += __shfl_xor(h2v[r], off);
            if (l15 == 0) {
                #pragma unroll
                for (int r = 0; r < 4; ++r) {
                    int row = rowbase + m * 16 + quad * 4 + r;
                    if (sMeta[row] == (unsigned char)t) wAcc += h2v[r] + dct;
                }
            }
        }
    }

    // ---- final reduce: wave -> block -> direct store (2 molecules, no atomics) ----
    #pragma unroll
    for (int off = 1; off < 64; off <<= 1) wAcc += __shfl_xor(wAcc, off);
    if (lane == 0) sPart[wv] = wAcc;
    __syncthreads();
    if (tid == 0) {
        out[2 * b]     = sPart[0] + sPart[1];
        out[2 * b + 1] = sPart[2] + sPart[3];
    }
}

extern "C" void kernel_launch(void* const* d_in, const int* in_sizes, int n_in,
                              void* d_out, int out_size, void* d_ws, size_t ws_size,
                              hipStream_t stream) {
    const float* x    = (const float*)d_in[0];
    const float* mask = (const float*)d_in[1];
    const float* W1   = (const float*)d_in[2];
    const float* b1   = (const float*)d_in[3];
    const float* W2   = (const float*)d_in[4];
    const float* b2   = (const float*)d_in[5];
    const float* W3   = (const float*)d_in[6];
    const float* b3   = (const float*)d_in[7];
    float* out = (float*)d_out;

    char* ws = (char*)d_ws;
    float*          dconst = (float*)(ws + WS_DCONST);
    unsigned short* W1S    = (unsigned short*)(ws + WS_W1S);
    unsigned short* W2T    = (unsigned short*)(ws + WS_W2T);

    k_setup<<<9, 256, 0, stream>>>(W1, b1, W2, b2, W3, b3, dconst, W1S, W2T);
    k_main<<<NMOL / 2, 256, 0, stream>>>(x, mask, W1S, b1, W2T, b2, W3, b3, dconst, out);
}

// Round 5
// 247.058 us; speedup vs baseline: 1.2269x; 1.2269x over previous
//
#include <hip/hip_runtime.h>
#include <stdint.h>

// Problem constants
#define NMOL 4096
#define NF 124
#define NT 8
#define ROWV 125               // x_padded row stride in floats

// ws layout (bytes)
#define WS_DCONST 0            // float[8]  (= T - c_t + b3_t)
#define WS_W1S    64           // ushort[8*64*128] bf16, XOR-16 swizzled (128 KB)
#define WS_W2T    131136       // ushort[8*16*64]  bf16, [t][g][h]       (16 KB)

#define HS 72                  // h1 row stride in shorts (144 B: 2-way banks, 16B-aligned)

typedef __attribute__((ext_vector_type(8))) short short8;
typedef __attribute__((ext_vector_type(4))) float floatx4;
typedef __attribute__((ext_vector_type(4), aligned(4))) float floatx4u;  // 4B-aligned vector load
typedef __attribute__((ext_vector_type(4))) unsigned int uint4v;

__device__ __forceinline__ unsigned short f2bf(float f) {
    unsigned u = __builtin_bit_cast(unsigned, f);
    u += 0x7fffu + ((u >> 16) & 1u);
    return (unsigned short)(u >> 16);
}
__device__ __forceinline__ unsigned pk2(float a, float b) {
    return (unsigned)f2bf(a) | ((unsigned)f2bf(b) << 16);
}
__device__ __forceinline__ void ld_lds16(const void* g, void* lds) {
    // per-lane 16B global->LDS; LDS dest = wave-uniform base + lane*16
    __builtin_amdgcn_global_load_lds(
        (const __attribute__((address_space(1))) unsigned int*)g,
        (__attribute__((address_space(3))) unsigned int*)lds, 16, 0, 0);
}

// ---------------- K1: setup (fp32 constants + weight prep) ----------------
__global__ __launch_bounds__(256) void k_setup(const float* __restrict__ W1,
                                               const float* __restrict__ b1,
                                               const float* __restrict__ W2,
                                               const float* __restrict__ b2,
                                               const float* __restrict__ W3,
                                               const float* __restrict__ b3,
                                               float* __restrict__ dconst,
                                               unsigned short* __restrict__ W1S,
                                               unsigned short* __restrict__ W2T) {
    int tid = threadIdx.x, b = blockIdx.x;
    if (b == 0) {
        __shared__ float c[NT];
        if (tid < 128) {           // exact fp32 constant c_t = MLP_t(0)
            int t = tid >> 4, g = tid & 15;
            float acc = b2[t * 16 + g];
            for (int h = 0; h < 64; ++h) {
                float h1 = b1[t * 64 + h];
                h1 = h1 > 0.f ? h1 : 0.f;
                acc += h1 * W2[(size_t)t * 1024 + h * 16 + g];
            }
            float h2 = acc > 0.f ? acc : 0.f;
            float v = h2 * W3[t * 16 + g];
            #pragma unroll
            for (int off = 1; off < 16; off <<= 1) v += __shfl_xor(v, off);
            if (g == 0) c[t] = v + b3[t];
        }
        __syncthreads();
        if (tid == 0) {
            float T_ = 0.f;
            for (int i = 0; i < NT; ++i) T_ += c[i];
            for (int i = 0; i < NT; ++i) dconst[i] = T_ - c[i] + b3[i];
        }
    } else {
        int t = b - 1;
        // W1 -> W1S: [h][chunk p = c ^ (h&15)][8 shorts], f padded to 128 w/ zeros
        const float* w1g = W1 + (size_t)t * NF * 64;
        unsigned short* dst = W1S + (size_t)t * 8192;
        for (int id = tid; id < 1024; id += 256) {   // (h, chunk cc)
            int h = id >> 4, cc = id & 15;
            unsigned u[4];
            #pragma unroll
            for (int j = 0; j < 4; ++j) {
                int f0 = cc * 8 + 2 * j;
                unsigned short lo = (f0 < NF)     ? f2bf(w1g[f0 * 64 + h])       : (unsigned short)0;
                unsigned short hi = (f0 + 1 < NF) ? f2bf(w1g[(f0 + 1) * 64 + h]) : (unsigned short)0;
                u[j] = (unsigned)lo | ((unsigned)hi << 16);
            }
            int p = cc ^ (h & 15);
            *(uint4v*)(dst + h * 128 + p * 8) = (uint4v){u[0], u[1], u[2], u[3]};
        }
        // W2 -> W2T: [t][g][h]
        unsigned short* d2 = W2T + (size_t)t * 1024;
        for (int i = tid; i < 1024; i += 256) {
            int g = i >> 6, h = i & 63;
            d2[i] = f2bf(W2[(size_t)t * 1024 + h * 16 + g]);
        }
    }
}

// ---------------- K2: single-pass MLP, A-frags in regs, W1 LDS double-buffered ----------------
__global__ __launch_bounds__(256, 3) void k_main(const float* __restrict__ x,
                                                 const float* __restrict__ mask,
                                                 const unsigned short* __restrict__ W1S,
                                                 const float* __restrict__ b1,
                                                 const unsigned short* __restrict__ W2T,
                                                 const float* __restrict__ b2,
                                                 const float* __restrict__ W3,
                                                 const float* __restrict__ dconst,
                                                 float* __restrict__ out) {
    __shared__ unsigned short sW[2][64 * 128];   // W1 double buffer (32 KB)
    __shared__ unsigned short sH[128 * HS];      // h1 bf16 (18 KB)
    __shared__ unsigned char  sMeta[128];
    __shared__ float          sDct[NT];
    __shared__ float          sPart[4];

    int b    = blockIdx.x;                       // 128 atoms = 2 molecules
    int tid  = threadIdx.x;
    int wv   = tid >> 6;
    int lane = tid & 63;
    int quad = lane >> 4, l15 = lane & 15;
    int rowbase = wv * 32;

    if (tid < NT) sDct[tid] = dconst[tid];

    // ---- meta: type + mask for this wave's 32 rows (written/read by same wave only) ----
    if (lane < 32) {
        int row = rowbase + lane;
        size_t atom = (size_t)b * 128 + row;
        float tf = x[atom * ROWV];
        float m  = mask[atom];
        sMeta[row] = (m != 0.f) ? (unsigned char)(int)tf : (unsigned char)255;
    }

    // ---- A-fragments: global -> regs, bf16-convert once, reused for all 8 types ----
    // lane holds A[row = rowbase + m*16 + l15][k = ks*32 + quad*8 + j], j=0..7
    short8 afrag[2][4];
    #pragma unroll
    for (int m = 0; m < 2; ++m) {
        size_t atom = (size_t)b * 128 + rowbase + m * 16 + l15;
        const float* rp = x + atom * ROWV + 1;
        #pragma unroll
        for (int ks = 0; ks < 4; ++ks) {
            int k0 = ks * 32 + quad * 8;
            floatx4 f0 = (floatx4)(*(const floatx4u*)(rp + k0));
            floatx4 f1 = (floatx4)0.f;
            if (!(ks == 3 && quad == 3))         // tail half would run past row (f>=124); W1S pad=0 anyway
                f1 = (floatx4)(*(const floatx4u*)(rp + k0 + 4));
            uint4v uu = (uint4v){pk2(f0[0], f0[1]), pk2(f0[2], f0[3]),
                                 pk2(f1[0], f1[1]), pk2(f1[2], f1[3])};
            afrag[m][ks] = __builtin_bit_cast(short8, uu);
        }
    }

    // ---- per-lane meta for epilogue rows (intra-wave DS ordering) ----
    int metar[2][4];
    #pragma unroll
    for (int m = 0; m < 2; ++m)
        #pragma unroll
        for (int r = 0; r < 4; ++r)
            metar[m][r] = sMeta[rowbase + m * 16 + quad * 4 + r];

    // ---- prefetch W1S[type 0] -> sW[0] (async, drained by barrier) ----
    {
        const char* src = (const char*)W1S + wv * 4096 + lane * 16;
        char*       dst = (char*)&sW[0][0] + wv * 4096;
        #pragma unroll
        for (int i = 0; i < 4; ++i) ld_lds16(src + i * 1024, dst + i * 1024);
    }

    float accR[2][4];
    #pragma unroll
    for (int m = 0; m < 2; ++m)
        #pragma unroll
        for (int r = 0; r < 4; ++r) accR[m][r] = 0.f;

    __syncthreads();

    #pragma unroll 1
    for (int t = 0; t < NT; ++t) {
        const unsigned short* wbuf = &sW[t & 1][0];
        if (t < 7) {   // prefetch next type's W1 into the other buffer
            const char* src = (const char*)W1S + (size_t)(t + 1) * 16384 + wv * 4096 + lane * 16;
            char*       dst = (char*)&sW[(t + 1) & 1][0] + wv * 4096;
            #pragma unroll
            for (int i = 0; i < 4; ++i) ld_lds16(src + i * 1024, dst + i * 1024);
        }

        float b1v[4];
        #pragma unroll
        for (int n = 0; n < 4; ++n) b1v[n] = b1[t * 64 + n * 16 + l15];

        // ---- layer 1: [32x128] x [128x64], B from LDS (swizzled, conflict-free) ----
        floatx4 c1[2][4];
        #pragma unroll
        for (int m = 0; m < 2; ++m)
            #pragma unroll
            for (int n = 0; n < 4; ++n) c1[m][n] = (floatx4)0.f;

        #pragma unroll
        for (int ks = 0; ks < 4; ++ks) {
            short8 bf[4];
            #pragma unroll
            for (int n = 0; n < 4; ++n)
                bf[n] = *(const short8*)(wbuf + (n * 16 + l15) * 128 + (((ks * 4 + quad) ^ l15) << 3));
            #pragma unroll
            for (int n = 0; n < 4; ++n) {
                c1[0][n] = __builtin_amdgcn_mfma_f32_16x16x32_bf16(afrag[0][ks], bf[n], c1[0][n], 0, 0, 0);
                c1[1][n] = __builtin_amdgcn_mfma_f32_16x16x32_bf16(afrag[1][ks], bf[n], c1[1][n], 0, 0, 0);
            }
        }

        // ---- h1 = relu(c1+b1) -> sH (own-wave rows, no barrier) ----
        #pragma unroll
        for (int m = 0; m < 2; ++m)
            #pragma unroll
            for (int n = 0; n < 4; ++n) {
                int col = n * 16 + l15;
                #pragma unroll
                for (int r = 0; r < 4; ++r) {
                    float v = c1[m][n][r] + b1v[n];
                    v = v > 0.f ? v : 0.f;
                    sH[(rowbase + m * 16 + quad * 4 + r) * HS + col] = f2bf(v);
                }
            }

        // ---- layer 2: [32x64] x [64x16] ----
        const unsigned short* w2t = W2T + (size_t)t * 1024;
        floatx4 c2[2];
        c2[0] = (floatx4)0.f; c2[1] = (floatx4)0.f;
        #pragma unroll
        for (int ks = 0; ks < 2; ++ks) {
            int ko = ks * 32 + quad * 8;
            short8 a0 = *(const short8*)(sH + (rowbase + l15) * HS + ko);
            short8 a1 = *(const short8*)(sH + (rowbase + 16 + l15) * HS + ko);
            short8 bw = *(const short8*)(w2t + l15 * 64 + ko);
            c2[0] = __builtin_amdgcn_mfma_f32_16x16x32_bf16(a0, bw, c2[0], 0, 0, 0);
            c2[1] = __builtin_amdgcn_mfma_f32_16x16x32_bf16(a1, bw, c2[1], 0, 0, 0);
        }

        // ---- layer 3 partial: masked accumulate, no shuffles here ----
        float b2v = b2[t * 16 + l15];
        float w3v = W3[t * 16 + l15];
        #pragma unroll
        for (int m = 0; m < 2; ++m)
            #pragma unroll
            for (int r = 0; r < 4; ++r) {
                float v = c2[m][r] + b2v;
                v = v > 0.f ? v : 0.f;
                v *= w3v;
                accR[m][r] += (metar[m][r] == t) ? v : 0.f;
            }

        __syncthreads();   // W double-buffer rotation (drains prefetch vmcnt)
    }

    // ---- epilogue: one reduction for all types ----
    #pragma unroll
    for (int m = 0; m < 2; ++m)
        #pragma unroll
        for (int r = 0; r < 4; ++r) {
            float v = accR[m][r];
            #pragma unroll
            for (int off = 1; off < 16; off <<= 1) v += __shfl_xor(v, off);
            accR[m][r] = v;
        }
    float wAcc = 0.f;
    if (l15 == 0) {
        #pragma unroll
        for (int m = 0; m < 2; ++m)
            #pragma unroll
            for (int r = 0; r < 4; ++r) {
                int mt = metar[m][r];
                if (mt != 255) wAcc += accR[m][r] + sDct[mt];
            }
    }
    wAcc += __shfl_xor(wAcc, 16);
    wAcc += __shfl_xor(wAcc, 32);
    if (lane == 0) sPart[wv] = wAcc;
    __syncthreads();
    if (tid == 0) {
        out[2 * b]     = sPart[0] + sPart[1];
        out[2 * b + 1] = sPart[2] + sPart[3];
    }
}

extern "C" void kernel_launch(void* const* d_in, const int* in_sizes, int n_in,
                              void* d_out, int out_size, void* d_ws, size_t ws_size,
                              hipStream_t stream) {
    const float* x    = (const float*)d_in[0];
    const float* mask = (const float*)d_in[1];
    const float* W1   = (const float*)d_in[2];
    const float* b1   = (const float*)d_in[3];
    const float* W2   = (const float*)d_in[4];
    const float* b2   = (const float*)d_in[5];
    const float* W3   = (const float*)d_in[6];
    const float* b3   = (const float*)d_in[7];
    float* out = (float*)d_out;

    char* ws = (char*)d_ws;
    float*          dconst = (float*)(ws + WS_DCONST);
    unsigned short* W1S    = (unsigned short*)(ws + WS_W1S);
    unsigned short* W2T    = (unsigned short*)(ws + WS_W2T);

    k_setup<<<9, 256, 0, stream>>>(W1, b1, W2, b2, W3, b3, dconst, W1S, W2T);
    k_main<<<NMOL / 2, 256, 0, stream>>>(x, mask, W1S, b1, W2T, b2, W3, dconst, out);
}

// Round 6
// 224.695 us; speedup vs baseline: 1.3490x; 1.0995x over previous
//
#include <hip/hip_runtime.h>
#include <stdint.h>

// Problem constants
#define NMOL 4096
#define NATOMS (NMOL * 64)     // 262144
#define NF 124
#define NT 8
#define ROWV 125               // x_padded row stride in floats

// ws layout (bytes)
#define WS_DCONST  0           // float[8]   (= T - c_t + b3_t)
#define WS_TOTALS  64          // uint[8]
#define WS_CURSOR  96          // uint[8]
#define WS_HIST    128         // uint[256*8]
#define WS_W1S     8320        // ushort[8*64*128] bf16, XOR-16 swizzled (128 KB)
#define WS_W2T     139392      // ushort[8*16*64]  bf16, [t][g][h]       (16 KB)
#define WS_TYPEBUF 155776      // uchar[NATOMS]
#define WS_LIST    417920      // uint[NATOMS]

#define HS 72                  // h1 row stride in shorts

typedef __attribute__((ext_vector_type(8))) short short8;
typedef __attribute__((ext_vector_type(4))) float floatx4;
typedef __attribute__((ext_vector_type(4), aligned(4))) float floatx4u;  // 4B-aligned vec load
typedef __attribute__((ext_vector_type(4))) unsigned int uint4v;

__device__ __forceinline__ unsigned short f2bf(float f) {
    unsigned u = __builtin_bit_cast(unsigned, f);
    u += 0x7fffu + ((u >> 16) & 1u);
    return (unsigned short)(u >> 16);
}
__device__ __forceinline__ unsigned pk2(float a, float b) {
    return (unsigned)f2bf(a) | ((unsigned)f2bf(b) << 16);
}
__device__ __forceinline__ void ld_lds16(const void* g, void* lds) {
    __builtin_amdgcn_global_load_lds(
        (const __attribute__((address_space(1))) unsigned int*)g,
        (__attribute__((address_space(3))) unsigned int*)lds, 16, 0, 0);
}

// ---------------- K1: histogram + typebuf + out-zero ----------------
__global__ __launch_bounds__(256) void k_hist(const float* __restrict__ x,
                                              const float* __restrict__ mask,
                                              unsigned* __restrict__ hist256,
                                              unsigned char* __restrict__ typebuf,
                                              float* __restrict__ out) {
    __shared__ unsigned hist[NT];
    int tid = threadIdx.x, b = blockIdx.x;
    if (tid < NT) hist[tid] = 0u;
    __syncthreads();
    int base = b * 1024;
    for (int i = 0; i < 4; ++i) {
        int atom = base + i * 256 + tid;
        float tf = x[(size_t)atom * ROWV];
        float m  = mask[atom];
        unsigned char tb = 0xFF;
        if (m != 0.0f) { tb = (unsigned char)(int)tf; atomicAdd(&hist[tb], 1u); }
        typebuf[atom] = tb;
    }
    if (b < 16) out[b * 256 + tid] = 0.0f;
    __syncthreads();
    if (tid < NT) hist256[b * NT + tid] = hist[tid];
}

// ---------------- K2: constants + hist reduce + prefix + weight prep ----------------
__global__ __launch_bounds__(256) void k_setup(const float* __restrict__ W1,
                                               const float* __restrict__ b1,
                                               const float* __restrict__ W2,
                                               const float* __restrict__ b2,
                                               const float* __restrict__ W3,
                                               const float* __restrict__ b3,
                                               const unsigned* __restrict__ hist256,
                                               float* __restrict__ dconst,
                                               unsigned* __restrict__ totals,
                                               unsigned* __restrict__ cursor,
                                               unsigned short* __restrict__ W1S,
                                               unsigned short* __restrict__ W2T) {
    int tid = threadIdx.x, b = blockIdx.x;
    if (b == 0) {
        __shared__ float c[NT];
        __shared__ unsigned part[16][NT];
        __shared__ unsigned tot[NT];
        if (tid < 128) {           // exact fp32 constant c_t = MLP_t(0)
            int t = tid >> 4, g = tid & 15;
            float acc = b2[t * 16 + g];
            for (int h = 0; h < 64; ++h) {
                float h1 = b1[t * 64 + h];
                h1 = h1 > 0.f ? h1 : 0.f;
                acc += h1 * W2[(size_t)t * 1024 + h * 16 + g];
            }
            float h2 = acc > 0.f ? acc : 0.f;
            float v = h2 * W3[t * 16 + g];
            #pragma unroll
            for (int off = 1; off < 16; off <<= 1) v += __shfl_xor(v, off);
            if (g == 0) c[t] = v + b3[t];
        }
        if (tid < 128) {           // reduce 256 block-histograms
            int t = tid & 7, chunk = tid >> 3;
            unsigned s = 0;
            for (int j = 0; j < 16; ++j) s += hist256[(chunk * 16 + j) * NT + t];
            part[chunk][t] = s;
        }
        __syncthreads();
        if (tid < NT) {
            unsigned s = 0;
            for (int j = 0; j < 16; ++j) s += part[j][tid];
            tot[tid] = s;
            totals[tid] = s;
        }
        __syncthreads();
        if (tid == 0) {
            float T_ = 0.f;
            for (int i = 0; i < NT; ++i) T_ += c[i];
            unsigned run = 0;
            for (int i = 0; i < NT; ++i) {
                dconst[i] = T_ - c[i] + b3[i];
                cursor[i] = run;
                run += tot[i];
            }
        }
    } else {
        int t = b - 1;
        // W1 -> W1S: [h][chunk p = cc ^ (h&15)][8 shorts], f padded to 128 w/ zeros
        const float* w1g = W1 + (size_t)t * NF * 64;
        unsigned short* dst = W1S + (size_t)t * 8192;
        for (int id = tid; id < 1024; id += 256) {
            int h = id >> 4, cc = id & 15;
            unsigned u[4];
            #pragma unroll
            for (int j = 0; j < 4; ++j) {
                int f0 = cc * 8 + 2 * j;
                unsigned short lo = (f0 < NF)     ? f2bf(w1g[f0 * 64 + h])       : (unsigned short)0;
                unsigned short hi = (f0 + 1 < NF) ? f2bf(w1g[(f0 + 1) * 64 + h]) : (unsigned short)0;
                u[j] = (unsigned)lo | ((unsigned)hi << 16);
            }
            int p = cc ^ (h & 15);
            *(uint4v*)(dst + h * 128 + p * 8) = (uint4v){u[0], u[1], u[2], u[3]};
        }
        // W2 -> W2T: [t][g][h]
        unsigned short* d2 = W2T + (size_t)t * 1024;
        for (int i = tid; i < 1024; i += 256) {
            int g = i >> 6, h = i & 63;
            d2[i] = f2bf(W2[(size_t)t * 1024 + h * 16 + g]);
        }
    }
}

// ---------------- K3: counting-sort scatter (one cursor atomic per type per block) ----
__global__ __launch_bounds__(256) void k_scatter(const unsigned char* __restrict__ typebuf,
                                                 unsigned* cursor, unsigned* list) {
    __shared__ unsigned hist[NT], basep[NT], cur[NT];
    int tid = threadIdx.x;
    if (tid < NT) { hist[tid] = 0u; cur[tid] = 0u; }
    __syncthreads();
    int base = blockIdx.x * 1024;
    unsigned char tb[4];
    for (int i = 0; i < 4; ++i) {
        tb[i] = typebuf[base + i * 256 + tid];
        if (tb[i] != 0xFF) atomicAdd(&hist[tb[i]], 1u);
    }
    __syncthreads();
    if (tid < NT && hist[tid]) basep[tid] = atomicAdd(&cursor[tid], hist[tid]);
    __syncthreads();
    for (int i = 0; i < 4; ++i) {
        if (tb[i] != 0xFF) {
            unsigned p = basep[tb[i]] + atomicAdd(&cur[tb[i]], 1u);
            list[p] = (unsigned)(base + i * 256 + tid);
        }
    }
}

// ---------------- K4: MLP over type-sorted atoms, A-frags in regs ----------------
// Block = 128 sorted atoms of ONE type. LDS 35.3 KB -> 4 blocks/CU.
__global__ __launch_bounds__(256, 4) void k_mlp(const float* __restrict__ x,
                                                const unsigned short* __restrict__ W1S,
                                                const float* __restrict__ b1,
                                                const unsigned short* __restrict__ W2T,
                                                const float* __restrict__ b2,
                                                const float* __restrict__ W3,
                                                const unsigned* __restrict__ totals,
                                                const float* __restrict__ dconst,
                                                const unsigned* __restrict__ list,
                                                float* __restrict__ out) {
    __shared__ unsigned short sW[64 * 128];   // W1 swizzled (16 KB)
    __shared__ unsigned short sH[128 * HS];   // h1 bf16 (18 KB)
    __shared__ unsigned sIds[128];

    // ---- locate (type, tile) from totals (block-uniform) ----
    unsigned g = blockIdx.x;
    unsigned cnt[NT], st[NT];
    {
        unsigned s = 0;
        for (int i = 0; i < NT; ++i) { cnt[i] = totals[i]; st[i] = s; s += cnt[i]; }
    }
    int t = -1; unsigned tile = 0;
    {
        unsigned tl = 0;
        for (int i = 0; i < NT; ++i) {
            unsigned nt_ = (cnt[i] + 127u) >> 7;
            if (t < 0 && g < tl + nt_) { t = i; tile = g - tl; }
            tl += nt_;
        }
    }
    if (t < 0) return;

    int valid = (int)cnt[t] - (int)(tile << 7);
    if (valid > 128) valid = 128;
    unsigned rowstart = st[t] + (tile << 7);

    int tid  = threadIdx.x;
    int wv   = tid >> 6;
    int lane = tid & 63;
    int quad = lane >> 4, l15 = lane & 15;
    int rowbase = wv * 32;

    // ---- stage W1S[t] -> sW (async 16B/lane) + ids ----
    {
        const char* src = (const char*)W1S + (size_t)t * 16384 + wv * 4096 + lane * 16;
        char*       dst = (char*)sW + wv * 4096;
        #pragma unroll
        for (int i = 0; i < 4; ++i) ld_lds16(src + i * 1024, dst + i * 1024);
    }
    if (tid < 128) sIds[tid] = list[rowstart + (tid < valid ? tid : 0)];  // clamp OOB rows

    float b1v[4];
    #pragma unroll
    for (int n = 0; n < 4; ++n) b1v[n] = b1[t * 64 + n * 16 + l15];

    __syncthreads();   // drains global_load_lds + sIds visible

    // ---- A-fragments: gather rows straight into regs, bf16 once ----
    short8 afrag[2][4];
    #pragma unroll
    for (int m = 0; m < 2; ++m) {
        unsigned atom = sIds[rowbase + m * 16 + l15];
        const float* rp = x + (size_t)atom * ROWV + 1;
        #pragma unroll
        for (int ks = 0; ks < 4; ++ks) {
            int k0 = ks * 32 + quad * 8;
            floatx4 f0 = (floatx4)(*(const floatx4u*)(rp + k0));
            floatx4 f1 = (floatx4)0.f;
            if (!(ks == 3 && quad == 3))         // f>=124 pad; W1S pad rows are zero
                f1 = (floatx4)(*(const floatx4u*)(rp + k0 + 4));
            uint4v uu = (uint4v){pk2(f0[0], f0[1]), pk2(f0[2], f0[3]),
                                 pk2(f1[0], f1[1]), pk2(f1[2], f1[3])};
            afrag[m][ks] = __builtin_bit_cast(short8, uu);
        }
    }

    // ---- layer 1: [32x128] x [128x64] ----
    floatx4 c1[2][4];
    #pragma unroll
    for (int m = 0; m < 2; ++m)
        #pragma unroll
        for (int n = 0; n < 4; ++n) c1[m][n] = (floatx4)0.f;

    #pragma unroll
    for (int ks = 0; ks < 4; ++ks) {
        short8 bf[4];
        #pragma unroll
        for (int n = 0; n < 4; ++n)
            bf[n] = *(const short8*)(sW + (n * 16 + l15) * 128 + (((ks * 4 + quad) ^ l15) << 3));
        #pragma unroll
        for (int n = 0; n < 4; ++n) {
            c1[0][n] = __builtin_amdgcn_mfma_f32_16x16x32_bf16(afrag[0][ks], bf[n], c1[0][n], 0, 0, 0);
            c1[1][n] = __builtin_amdgcn_mfma_f32_16x16x32_bf16(afrag[1][ks], bf[n], c1[1][n], 0, 0, 0);
        }
    }

    // ---- h1 = relu(c1+b1) -> sH (own-wave rows, no barrier) ----
    #pragma unroll
    for (int m = 0; m < 2; ++m)
        #pragma unroll
        for (int n = 0; n < 4; ++n) {
            int col = n * 16 + l15;
            #pragma unroll
            for (int r = 0; r < 4; ++r) {
                float v = c1[m][n][r] + b1v[n];
                v = v > 0.f ? v : 0.f;
                sH[(rowbase + m * 16 + quad * 4 + r) * HS + col] = f2bf(v);
            }
        }

    // ---- layer 2: [32x64] x [64x16] ----
    const unsigned short* w2t = W2T + (size_t)t * 1024;
    floatx4 c2[2];
    c2[0] = (floatx4)0.f; c2[1] = (floatx4)0.f;
    #pragma unroll
    for (int ks = 0; ks < 2; ++ks) {
        int ko = ks * 32 + quad * 8;
        short8 a0 = *(const short8*)(sH + (rowbase + l15) * HS + ko);
        short8 a1 = *(const short8*)(sH + (rowbase + 16 + l15) * HS + ko);
        short8 bw = *(const short8*)(w2t + l15 * 64 + ko);
        c2[0] = __builtin_amdgcn_mfma_f32_16x16x32_bf16(a0, bw, c2[0], 0, 0, 0);
        c2[1] = __builtin_amdgcn_mfma_f32_16x16x32_bf16(a1, bw, c2[1], 0, 0, 0);
    }

    // ---- layer 3 + constant + atomic accumulate ----
    float b2v = b2[t * 16 + l15];
    float w3v = W3[t * 16 + l15];
    float dct = dconst[t];   // includes b3
    #pragma unroll
    for (int m = 0; m < 2; ++m) {
        float h2v[4];
        #pragma unroll
        for (int r = 0; r < 4; ++r) {
            float v = c2[m][r] + b2v;
            v = v > 0.f ? v : 0.f;
            h2v[r] = v * w3v;
        }
        #pragma unroll
        for (int off = 1; off < 16; off <<= 1)
            #pragma unroll
            for (int r = 0; r < 4; ++r) h2v[r] += __shfl_xor(h2v[r], off);
        if (l15 == 0) {
            #pragma unroll
            for (int r = 0; r < 4; ++r) {
                int row = rowbase + m * 16 + quad * 4 + r;
                if (row < valid) {
                    unsigned atom = sIds[row];
                    atomicAdd(&out[atom >> 6], h2v[r] + dct);
                }
            }
        }
    }
}

extern "C" void kernel_launch(void* const* d_in, const int* in_sizes, int n_in,
                              void* d_out, int out_size, void* d_ws, size_t ws_size,
                              hipStream_t stream) {
    const float* x    = (const float*)d_in[0];
    const float* mask = (const float*)d_in[1];
    const float* W1   = (const float*)d_in[2];
    const float* b1   = (const float*)d_in[3];
    const float* W2   = (const float*)d_in[4];
    const float* b2   = (const float*)d_in[5];
    const float* W3   = (const float*)d_in[6];
    const float* b3   = (const float*)d_in[7];
    float* out = (float*)d_out;

    char* ws = (char*)d_ws;
    float*          dconst  = (float*)(ws + WS_DCONST);
    unsigned*       totals  = (unsigned*)(ws + WS_TOTALS);
    unsigned*       cursor  = (unsigned*)(ws + WS_CURSOR);
    unsigned*       hist256 = (unsigned*)(ws + WS_HIST);
    unsigned short* W1S     = (unsigned short*)(ws + WS_W1S);
    unsigned short* W2T     = (unsigned short*)(ws + WS_W2T);
    unsigned char*  typebuf = (unsigned char*)(ws + WS_TYPEBUF);
    unsigned*       list    = (unsigned*)(ws + WS_LIST);

    k_hist<<<256, 256, 0, stream>>>(x, mask, hist256, typebuf, out);
    k_setup<<<9, 256, 0, stream>>>(W1, b1, W2, b2, W3, b3, hist256,
                                   dconst, totals, cursor, W1S, W2T);
    k_scatter<<<256, 256, 0, stream>>>(typebuf, cursor, list);
    // max tiles: 2048 + 7 (per-type rounding)
    k_mlp<<<2055, 256, 0, stream>>>(x, W1S, b1, W2T, b2, W3,
                                    totals, dconst, list, out);
}

// Round 7
// 217.270 us; speedup vs baseline: 1.3951x; 1.0342x over previous
//
#include <hip/hip_runtime.h>
#include <stdint.h>

// Problem constants
#define NMOL 4096
#define NATOMS (NMOL * 64)     // 262144
#define NF 124
#define NT 8
#define ROWV 125               // x_padded row stride in floats
#define CAP 65536              // list slots per type (worst case all atoms one type)

// ws layout (bytes)
#define WS_DCONST  0           // float[8]   (= T - c_t + b3_t)
#define WS_CURSOR  64          // uint[8]    (preset to t*CAP; post-sort = t*CAP + count_t)
#define WS_W1S     128         // ushort[8*64*128] bf16, XOR-16 swizzled (128 KB)
#define WS_W2T     131200      // ushort[8*16*64]  bf16, [t][g][h]       (16 KB)
#define WS_LIST    147712      // uint[NT*CAP]                           (2 MB)

#define HS 72                  // h1 row stride in shorts

typedef __attribute__((ext_vector_type(8))) short short8;
typedef __attribute__((ext_vector_type(4))) float floatx4;
typedef __attribute__((ext_vector_type(4), aligned(4))) float floatx4u;  // 4B-aligned vec load
typedef __attribute__((ext_vector_type(4))) unsigned int uint4v;

__device__ __forceinline__ unsigned short f2bf(float f) {
    unsigned u = __builtin_bit_cast(unsigned, f);
    u += 0x7fffu + ((u >> 16) & 1u);
    return (unsigned short)(u >> 16);
}
__device__ __forceinline__ unsigned pk2(float a, float b) {
    return (unsigned)f2bf(a) | ((unsigned)f2bf(b) << 16);
}
__device__ __forceinline__ void ld_lds16(const void* g, void* lds) {
    __builtin_amdgcn_global_load_lds(
        (const __attribute__((address_space(1))) unsigned int*)g,
        (__attribute__((address_space(3))) unsigned int*)lds, 16, 0, 0);
}

// ---------------- K1: setup (constants + cursors + weight prep + out-zero) ----------------
// b==0: dconst fp32 + cursor[t]=t*CAP; b 1..8: W1S/W2T for type b-1; b 9..24: zero out
__global__ __launch_bounds__(256) void k_setup(const float* __restrict__ W1,
                                               const float* __restrict__ b1,
                                               const float* __restrict__ W2,
                                               const float* __restrict__ b2,
                                               const float* __restrict__ W3,
                                               const float* __restrict__ b3,
                                               float* __restrict__ dconst,
                                               unsigned* __restrict__ cursor,
                                               unsigned short* __restrict__ W1S,
                                               unsigned short* __restrict__ W2T,
                                               float* __restrict__ out) {
    int tid = threadIdx.x, b = blockIdx.x;
    if (b == 0) {
        __shared__ float c[NT];
        if (tid < 128) {           // exact fp32 constant c_t = MLP_t(0)
            int t = tid >> 4, g = tid & 15;
            float acc = b2[t * 16 + g];
            for (int h = 0; h < 64; ++h) {
                float h1 = b1[t * 64 + h];
                h1 = h1 > 0.f ? h1 : 0.f;
                acc += h1 * W2[(size_t)t * 1024 + h * 16 + g];
            }
            float h2 = acc > 0.f ? acc : 0.f;
            float v = h2 * W3[t * 16 + g];
            #pragma unroll
            for (int off = 1; off < 16; off <<= 1) v += __shfl_xor(v, off);
            if (g == 0) c[t] = v + b3[t];
        }
        if (tid < NT) cursor[tid] = (unsigned)(tid * CAP);
        __syncthreads();
        if (tid == 0) {
            float T_ = 0.f;
            for (int i = 0; i < NT; ++i) T_ += c[i];
            for (int i = 0; i < NT; ++i) dconst[i] = T_ - c[i] + b3[i];
        }
    } else if (b <= 8) {
        int t = b - 1;
        // W1 -> W1S: [h][chunk p = cc ^ (h&15)][8 shorts], f padded to 128 w/ zeros
        const float* w1g = W1 + (size_t)t * NF * 64;
        unsigned short* dst = W1S + (size_t)t * 8192;
        for (int id = tid; id < 1024; id += 256) {
            int h = id >> 4, cc = id & 15;
            unsigned u[4];
            #pragma unroll
            for (int j = 0; j < 4; ++j) {
                int f0 = cc * 8 + 2 * j;
                unsigned short lo = (f0 < NF)     ? f2bf(w1g[f0 * 64 + h])       : (unsigned short)0;
                unsigned short hi = (f0 + 1 < NF) ? f2bf(w1g[(f0 + 1) * 64 + h]) : (unsigned short)0;
                u[j] = (unsigned)lo | ((unsigned)hi << 16);
            }
            int p = cc ^ (h & 15);
            *(uint4v*)(dst + h * 128 + p * 8) = (uint4v){u[0], u[1], u[2], u[3]};
        }
        // W2 -> W2T: [t][g][h]
        unsigned short* d2 = W2T + (size_t)t * 1024;
        for (int i = tid; i < 1024; i += 256) {
            int g = i >> 6, h = i & 63;
            d2[i] = f2bf(W2[(size_t)t * 1024 + h * 16 + g]);
        }
    } else {
        out[(b - 9) * 256 + tid] = 0.0f;
    }
}

// ---------------- K2: one-pass type sort into fixed segments ----------------
__global__ __launch_bounds__(256) void k_sort(const float* __restrict__ x,
                                              const float* __restrict__ mask,
                                              unsigned* __restrict__ cursor,
                                              unsigned* __restrict__ list) {
    __shared__ unsigned hist[NT], basep[NT], cur[NT];
    int tid = threadIdx.x;
    if (tid < NT) { hist[tid] = 0u; cur[tid] = 0u; }
    __syncthreads();
    int base = blockIdx.x * 1024;
    unsigned char tb[4];
    for (int i = 0; i < 4; ++i) {
        int atom = base + i * 256 + tid;
        float tf = x[(size_t)atom * ROWV];
        float m  = mask[atom];
        tb[i] = 0xFF;
        if (m != 0.0f) { tb[i] = (unsigned char)(int)tf; atomicAdd(&hist[tb[i]], 1u); }
    }
    __syncthreads();
    if (tid < NT && hist[tid]) basep[tid] = atomicAdd(&cursor[tid], hist[tid]);
    __syncthreads();
    for (int i = 0; i < 4; ++i) {
        if (tb[i] != 0xFF) {
            unsigned p = basep[tb[i]] + atomicAdd(&cur[tb[i]], 1u);
            list[p] = (unsigned)(base + i * 256 + tid);
        }
    }
}

// ---------------- K3: MLP over type-sorted atoms, A-frags in regs ----------------
// Block = 128 sorted atoms of ONE type. LDS 35.3 KB -> 4 blocks/CU.
__global__ __launch_bounds__(256, 4) void k_mlp(const float* __restrict__ x,
                                                const unsigned short* __restrict__ W1S,
                                                const float* __restrict__ b1,
                                                const unsigned short* __restrict__ W2T,
                                                const float* __restrict__ b2,
                                                const float* __restrict__ W3,
                                                const unsigned* __restrict__ cursor,
                                                const float* __restrict__ dconst,
                                                const unsigned* __restrict__ list,
                                                float* __restrict__ out) {
    __shared__ unsigned short sW[64 * 128];   // W1 swizzled (16 KB)
    __shared__ unsigned short sH[128 * HS];   // h1 bf16 (18 KB)
    __shared__ unsigned sIds[128];

    int t    = blockIdx.x >> 9;               // 512 tiles per type segment
    int tile = blockIdx.x & 511;
    int cnt  = (int)(cursor[t] - (unsigned)(t * CAP));
    int valid = cnt - (tile << 7);
    if (valid <= 0) return;
    if (valid > 128) valid = 128;
    int rowstart = t * CAP + (tile << 7);

    int tid  = threadIdx.x;
    int wv   = tid >> 6;
    int lane = tid & 63;
    int quad = lane >> 4, l15 = lane & 15;
    int rowbase = wv * 32;

    // ---- stage W1S[t] -> sW (async 16B/lane) + ids ----
    {
        const char* src = (const char*)W1S + (size_t)t * 16384 + wv * 4096 + lane * 16;
        char*       dst = (char*)sW + wv * 4096;
        #pragma unroll
        for (int i = 0; i < 4; ++i) ld_lds16(src + i * 1024, dst + i * 1024);
    }
    if (tid < 128) sIds[tid] = list[rowstart + (tid < valid ? tid : 0)];  // clamp OOB rows

    float b1v[4];
    #pragma unroll
    for (int n = 0; n < 4; ++n) b1v[n] = b1[t * 64 + n * 16 + l15];

    __syncthreads();   // drains global_load_lds + sIds visible

    // ---- A-fragments: gather rows straight into regs, bf16 once ----
    short8 afrag[2][4];
    #pragma unroll
    for (int m = 0; m < 2; ++m) {
        unsigned atom = sIds[rowbase + m * 16 + l15];
        const float* rp = x + (size_t)atom * ROWV + 1;
        #pragma unroll
        for (int ks = 0; ks < 4; ++ks) {
            int k0 = ks * 32 + quad * 8;
            floatx4 f0 = (floatx4)(*(const floatx4u*)(rp + k0));
            floatx4 f1 = (floatx4)0.f;
            if (!(ks == 3 && quad == 3))         // f>=124 pad; W1S pad rows are zero
                f1 = (floatx4)(*(const floatx4u*)(rp + k0 + 4));
            uint4v uu = (uint4v){pk2(f0[0], f0[1]), pk2(f0[2], f0[3]),
                                 pk2(f1[0], f1[1]), pk2(f1[2], f1[3])};
            afrag[m][ks] = __builtin_bit_cast(short8, uu);
        }
    }

    // ---- layer 1: [32x128] x [128x64] ----
    floatx4 c1[2][4];
    #pragma unroll
    for (int m = 0; m < 2; ++m)
        #pragma unroll
        for (int n = 0; n < 4; ++n) c1[m][n] = (floatx4)0.f;

    #pragma unroll
    for (int ks = 0; ks < 4; ++ks) {
        short8 bf[4];
        #pragma unroll
        for (int n = 0; n < 4; ++n)
            bf[n] = *(const short8*)(sW + (n * 16 + l15) * 128 + (((ks * 4 + quad) ^ l15) << 3));
        #pragma unroll
        for (int n = 0; n < 4; ++n) {
            c1[0][n] = __builtin_amdgcn_mfma_f32_16x16x32_bf16(afrag[0][ks], bf[n], c1[0][n], 0, 0, 0);
            c1[1][n] = __builtin_amdgcn_mfma_f32_16x16x32_bf16(afrag[1][ks], bf[n], c1[1][n], 0, 0, 0);
        }
    }

    // ---- h1 = relu(c1+b1) -> sH (own-wave rows, no barrier) ----
    #pragma unroll
    for (int m = 0; m < 2; ++m)
        #pragma unroll
        for (int n = 0; n < 4; ++n) {
            int col = n * 16 + l15;
            #pragma unroll
            for (int r = 0; r < 4; ++r) {
                float v = c1[m][n][r] + b1v[n];
                v = v > 0.f ? v : 0.f;
                sH[(rowbase + m * 16 + quad * 4 + r) * HS + col] = f2bf(v);
            }
        }

    // ---- layer 2: [32x64] x [64x16] ----
    const unsigned short* w2t = W2T + (size_t)t * 1024;
    floatx4 c2[2];
    c2[0] = (floatx4)0.f; c2[1] = (floatx4)0.f;
    #pragma unroll
    for (int ks = 0; ks < 2; ++ks) {
        int ko = ks * 32 + quad * 8;
        short8 a0 = *(const short8*)(sH + (rowbase + l15) * HS + ko);
        short8 a1 = *(const short8*)(sH + (rowbase + 16 + l15) * HS + ko);
        short8 bw = *(const short8*)(w2t + l15 * 64 + ko);
        c2[0] = __builtin_amdgcn_mfma_f32_16x16x32_bf16(a0, bw, c2[0], 0, 0, 0);
        c2[1] = __builtin_amdgcn_mfma_f32_16x16x32_bf16(a1, bw, c2[1], 0, 0, 0);
    }

    // ---- layer 3 + constant + atomic accumulate ----
    float b2v = b2[t * 16 + l15];
    float w3v = W3[t * 16 + l15];
    float dct = dconst[t];   // includes b3
    #pragma unroll
    for (int m = 0; m < 2; ++m) {
        float h2v[4];
        #pragma unroll
        for (int r = 0; r < 4; ++r) {
            float v = c2[m][r] + b2v;
            v = v > 0.f ? v : 0.f;
            h2v[r] = v * w3v;
        }
        #pragma unroll
        for (int off = 1; off < 16; off <<= 1)
            #pragma unroll
            for (int r = 0; r < 4; ++r) h2v[r] += __shfl_xor(h2v[r], off);
        if (l15 == 0) {
            #pragma unroll
            for (int r = 0; r < 4; ++r) {
                int row = rowbase + m * 16 + quad * 4 + r;
                if (row < valid) {
                    unsigned atom = sIds[row];
                    atomicAdd(&out[atom >> 6], h2v[r] + dct);
                }
            }
        }
    }
}

extern "C" void kernel_launch(void* const* d_in, const int* in_sizes, int n_in,
                              void* d_out, int out_size, void* d_ws, size_t ws_size,
                              hipStream_t stream) {
    const float* x    = (const float*)d_in[0];
    const float* mask = (const float*)d_in[1];
    const float* W1   = (const float*)d_in[2];
    const float* b1   = (const float*)d_in[3];
    const float* W2   = (const float*)d_in[4];
    const float* b2   = (const float*)d_in[5];
    const float* W3   = (const float*)d_in[6];
    const float* b3   = (const float*)d_in[7];
    float* out = (float*)d_out;

    char* ws = (char*)d_ws;
    float*          dconst = (float*)(ws + WS_DCONST);
    unsigned*       cursor = (unsigned*)(ws + WS_CURSOR);
    unsigned short* W1S    = (unsigned short*)(ws + WS_W1S);
    unsigned short* W2T    = (unsigned short*)(ws + WS_W2T);
    unsigned*       list   = (unsigned*)(ws + WS_LIST);

    k_setup<<<25, 256, 0, stream>>>(W1, b1, W2, b2, W3, b3, dconst, cursor, W1S, W2T, out);
    k_sort<<<256, 256, 0, stream>>>(x, mask, cursor, list);
    k_mlp<<<NT * (CAP / 128), 256, 0, stream>>>(x, W1S, b1, W2T, b2, W3,
                                                cursor, dconst, list, out);
}